// Round 5
// baseline (250.792 us; speedup 1.0000x reference)
//
#include <hip/hip_runtime.h>

#define N_NODES 50000
#define N_EDGES 400000
#define DIM 160
#define NB 64
#define CUTOFF 5.0f
#define LN_EPS 1e-5f
#define PI_F 3.14159265358979323846f

// Workspace (ints): [0..15] ew(float)+pad | deg[N] | offs[50004] | cursor[N] | esrc[E]
#define WS_DEG    16
#define WS_OFFS   (WS_DEG + N_NODES)        // 16B aligned
#define WS_CURSOR (WS_OFFS + 50004)         // 16B aligned
#define WS_ESRC   (WS_CURSOR + N_NODES)

// ---------------------------------------------------------------------------
// K1: thread-per-edge. dst histogram (int atomics) + edge_w sigmoid sum.
// ---------------------------------------------------------------------------
__global__ __launch_bounds__(256) void hist_ew(
    const int* __restrict__ ei, const float* __restrict__ pos,
    const float* __restrict__ centers, const float* __restrict__ widths,
    const float* __restrict__ proj_w, const float* __restrict__ proj_b,
    int* __restrict__ deg, float* __restrict__ ew_accum)
{
    __shared__ float sc_c[NB], sc_iw[NB], sc_p[NB];
    if (threadIdx.x < NB) {
        sc_c[threadIdx.x]  = centers[threadIdx.x];
        sc_iw[threadIdx.x] = 1.0f / widths[threadIdx.x];
        sc_p[threadIdx.x]  = proj_w[threadIdx.x];
    }
    __syncthreads();

    const float bias = proj_b[0];
    const int e = blockIdx.x * blockDim.x + threadIdx.x;
    float sig = 0.0f;
    if (e < N_EDGES) {
        const int s = ei[e];
        const int d = ei[N_EDGES + e];
        atomicAdd(&deg[d], 1);

        const float dx = pos[3 * s]     - pos[3 * d];
        const float dy = pos[3 * s + 1] - pos[3 * d + 1];
        const float dz = pos[3 * s + 2] - pos[3 * d + 2];
        const float dist = sqrtf(dx * dx + dy * dy + dz * dz);

        float z = 0.0f;
        #pragma unroll 8
        for (int b = 0; b < NB; ++b) {
            const float t = (dist - sc_c[b]) * sc_iw[b];
            z += __expf(-0.5f * t * t) * sc_p[b];
        }
        const float cut = (dist <= CUTOFF)
                        ? 0.5f * (__cosf(PI_F * dist * (1.0f / CUTOFF)) + 1.0f)
                        : 0.0f;
        sig = 1.0f / (1.0f + __expf(-(z * cut + bias)));
    }

    #pragma unroll
    for (int off = 32; off > 0; off >>= 1) sig += __shfl_xor(sig, off);
    __shared__ float red[4];
    if ((threadIdx.x & 63) == 0) red[threadIdx.x >> 6] = sig;
    __syncthreads();
    if (threadIdx.x == 0)
        atomicAdd(ew_accum, red[0] + red[1] + red[2] + red[3]);
}

// ---------------------------------------------------------------------------
// K2: single-block exclusive scan, int4-vectorized.
// ---------------------------------------------------------------------------
__global__ __launch_bounds__(1024) void scan_deg(
    const int* __restrict__ deg, int* __restrict__ offs, int* __restrict__ cursor)
{
    __shared__ int wsum[16];
    const int tid = threadIdx.x, lane = tid & 63, w = tid >> 6;
    const int4* d4 = (const int4*)deg;
    int4* o4 = (int4*)offs;
    int4* c4 = (int4*)cursor;
    int carry = 0;
    const int NV = N_NODES / 4;
    for (int base = 0; base < NV; base += 1024) {
        const int i = base + tid;
        int4 v = make_int4(0, 0, 0, 0);
        if (i < NV) v = d4[i];
        const int loc = v.x + v.y + v.z + v.w;
        int sc = loc;
        #pragma unroll
        for (int off = 1; off < 64; off <<= 1) {
            const int t = __shfl_up(sc, off);
            if (lane >= off) sc += t;
        }
        if (lane == 63) wsum[w] = sc;
        __syncthreads();
        if (w == 0) {
            int s = (lane < 16) ? wsum[lane] : 0;
            #pragma unroll
            for (int off = 1; off < 16; off <<= 1) {
                const int t = __shfl_up(s, off);
                if (lane >= off) s += t;
            }
            if (lane < 16) wsum[lane] = s;
        }
        __syncthreads();
        const int wpre = (w > 0) ? wsum[w - 1] : 0;
        const int excl = carry + wpre + sc - loc;
        if (i < NV) {
            int4 o;
            o.x = excl;
            o.y = o.x + v.x;
            o.z = o.y + v.y;
            o.w = o.z + v.z;
            o4[i] = o;
            c4[i] = o;
        }
        carry += wsum[15];
        __syncthreads();
    }
    if (tid == 0) offs[N_NODES] = carry;
}

// ---------------------------------------------------------------------------
// K3: thread-per-edge fill of CSR edge-source list.
// ---------------------------------------------------------------------------
__global__ __launch_bounds__(256) void fill_csr(
    const int* __restrict__ ei, int* __restrict__ cursor, int* __restrict__ esrc)
{
    const int e = blockIdx.x * blockDim.x + threadIdx.x;
    if (e >= N_EDGES) return;
    const int s = ei[e];
    const int d = ei[N_EDGES + e];
    const int p = atomicAdd(&cursor[d], 1);
    esrc[p] = s;
}

// ---------------------------------------------------------------------------
// K4: wave-per-node gather, edge loop unrolled x4 (deeper MLP).
// ---------------------------------------------------------------------------
__global__ __launch_bounds__(256) void gather_pass(
    const float* __restrict__ x, const int* __restrict__ offs,
    const int* __restrict__ esrc, float* __restrict__ agg)
{
    const int lane = threadIdx.x & 63;
    const int n    = (blockIdx.x * blockDim.x + threadIdx.x) >> 6;
    if (n >= N_NODES) return;

    const int beg = offs[n];
    const int end = offs[n + 1];

    float4 acc = make_float4(0.f, 0.f, 0.f, 0.f);
    for (int k0 = beg; k0 < end; k0 += 64) {
        const int cnt = min(64, end - k0);
        const int sv  = (lane < cnt) ? esrc[k0 + lane] : 0;
        int j = 0;
        for (; j + 4 <= cnt; j += 4) {
            const int s0 = __shfl(sv, j);
            const int s1 = __shfl(sv, j + 1);
            const int s2 = __shfl(sv, j + 2);
            const int s3 = __shfl(sv, j + 3);
            if (lane < 40) {
                const float4 v0 = ((const float4*)(x + (long)s0 * DIM))[lane];
                const float4 v1 = ((const float4*)(x + (long)s1 * DIM))[lane];
                const float4 v2 = ((const float4*)(x + (long)s2 * DIM))[lane];
                const float4 v3 = ((const float4*)(x + (long)s3 * DIM))[lane];
                acc.x += (v0.x + v1.x) + (v2.x + v3.x);
                acc.y += (v0.y + v1.y) + (v2.y + v3.y);
                acc.z += (v0.z + v1.z) + (v2.z + v3.z);
                acc.w += (v0.w + v1.w) + (v2.w + v3.w);
            }
        }
        for (; j < cnt; ++j) {
            const int s0 = __shfl(sv, j);
            if (lane < 40) {
                const float4 v0 = ((const float4*)(x + (long)s0 * DIM))[lane];
                acc.x += v0.x; acc.y += v0.y; acc.z += v0.z; acc.w += v0.w;
            }
        }
    }
    if (lane < 40)
        ((float4*)(agg + (long)n * DIM))[lane] = acc;
}

// ---------------------------------------------------------------------------
// K5a: scalar channel, lane-owns-node. acc[64] in VGPRs (launch_bounds(…,1)
// prevents the round-4 spill-to-scratch at VGPR=60). Weights via wave-uniform
// s_load (SGPR operand in v_fmac). In-place on row[0:64].
// ---------------------------------------------------------------------------
__global__ __launch_bounds__(256, 1) void scalar_pass(
    float* __restrict__ agg, const float* __restrict__ W0,
    const float* __restrict__ ln_gamma, const float* __restrict__ ln_beta,
    const float* __restrict__ ew_accum)
{
    const int node  = blockIdx.x * 256 + threadIdx.x;
    const bool valid = node < N_NODES;
    const int nc    = valid ? node : (N_NODES - 1);
    float* row = agg + (long)nc * DIM;
    const float4* row4 = (const float4*)row;

    const float ew   = ew_accum[0] * (1.0f / 400000.0f);
    const float s_m0 = ew * 0.125f;                 // / sqrt(64)

    float acc[64];
    #pragma unroll
    for (int j = 0; j < 64; ++j) acc[j] = 0.0f;

    #pragma unroll 2
    for (int q = 0; q < 16; ++q) {          // k = 4q + r
        const float4 a4 = row4[q];          // per-lane diverged load
        const float* w = W0 + q * 256;      // uniform -> SGPRs
        #pragma unroll
        for (int j = 0; j < 64; ++j) acc[j] = fmaf(a4.x, w[j],       acc[j]);
        #pragma unroll
        for (int j = 0; j < 64; ++j) acc[j] = fmaf(a4.y, w[64 + j],  acc[j]);
        #pragma unroll
        for (int j = 0; j < 64; ++j) acc[j] = fmaf(a4.z, w[128 + j], acc[j]);
        #pragma unroll
        for (int j = 0; j < 64; ++j) acc[j] = fmaf(a4.w, w[192 + j], acc[j]);
    }

    float mu = 0.0f;
    #pragma unroll
    for (int j = 0; j < 64; ++j) { acc[j] *= s_m0; mu += acc[j]; }
    mu *= (1.0f / 64.0f);
    float var = 0.0f;
    #pragma unroll
    for (int j = 0; j < 64; ++j) { const float d = acc[j] - mu; var = fmaf(d, d, var); }
    var *= (1.0f / 64.0f);
    const float rstd = rsqrtf(var + LN_EPS);

    if (valid) {
        float4* ro4 = (float4*)row;
        #pragma unroll
        for (int q = 0; q < 16; ++q) {
            const float t0 = (acc[4 * q]     - mu) * rstd * ln_gamma[4 * q]     + ln_beta[4 * q];
            const float t1 = (acc[4 * q + 1] - mu) * rstd * ln_gamma[4 * q + 1] + ln_beta[4 * q + 1];
            const float t2 = (acc[4 * q + 2] - mu) * rstd * ln_gamma[4 * q + 2] + ln_beta[4 * q + 2];
            const float t3 = (acc[4 * q + 3] - mu) * rstd * ln_gamma[4 * q + 3] + ln_beta[4 * q + 3];
            float4 o;
            o.x = t0 / (1.0f + __expf(-t0));
            o.y = t1 / (1.0f + __expf(-t1));
            o.z = t2 / (1.0f + __expf(-t2));
            o.w = t3 / (1.0f + __expf(-t3));
            ro4[q] = o;
        }
    }
}

// ---------------------------------------------------------------------------
// K5b: vector channel, lane-owns-node. o[96] in VGPRs, weights via s_load.
// In-place on row[64:160]. Independent of scalar_pass (disjoint row halves).
// ---------------------------------------------------------------------------
__global__ __launch_bounds__(256, 1) void vector_pass(
    float* __restrict__ agg, const float* __restrict__ W1,
    const float* __restrict__ ew_accum)
{
    const int node  = blockIdx.x * 256 + threadIdx.x;
    const bool valid = node < N_NODES;
    const int nc    = valid ? node : (N_NODES - 1);
    float* row = agg + (long)nc * DIM + 64;
    const float4* r4 = (const float4*)row;

    const float ew   = ew_accum[0] * (1.0f / 400000.0f);
    const float s_m1 = ew * 0.17677669529663687f;   // / sqrt(32)

    float o[96];
    #pragma unroll
    for (int m = 0; m < 96; ++m) o[m] = 0.0f;

    #pragma unroll 1
    for (int t = 0; t < 8; ++t) {            // cp = 4t + r
        const float4 v0 = r4[3 * t];
        const float4 v1 = r4[3 * t + 1];
        const float4 v2 = r4[3 * t + 2];
        const float a[12] = { v0.x, v0.y, v0.z, v0.w,
                              v1.x, v1.y, v1.z, v1.w,
                              v2.x, v2.y, v2.z, v2.w };
        const float* w = W1 + 4 * t * 32;    // uniform -> SGPRs
        #pragma unroll
        for (int r = 0; r < 4; ++r) {
            const float a0 = a[3 * r];
            const float a1 = a[3 * r + 1];
            const float a2 = a[3 * r + 2];
            #pragma unroll
            for (int c = 0; c < 32; ++c) {
                const float wc = w[r * 32 + c];
                o[3 * c]     = fmaf(wc, a0, o[3 * c]);
                o[3 * c + 1] = fmaf(wc, a1, o[3 * c + 1]);
                o[3 * c + 2] = fmaf(wc, a2, o[3 * c + 2]);
            }
        }
    }

    if (valid) {
        float4* ro4 = (float4*)row;
        #pragma unroll
        for (int q = 0; q < 24; ++q) {
            float4 ov;
            ov.x = o[4 * q]     * s_m1;
            ov.y = o[4 * q + 1] * s_m1;
            ov.z = o[4 * q + 2] * s_m1;
            ov.w = o[4 * q + 3] * s_m1;
            ro4[q] = ov;
        }
    }
}

extern "C" void kernel_launch(void* const* d_in, const int* in_sizes, int n_in,
                              void* d_out, int out_size, void* d_ws, size_t ws_size,
                              hipStream_t stream) {
    const float* x       = (const float*)d_in[0];
    const float* pos     = (const float*)d_in[1];
    const int*   ei      = (const int*)d_in[2];
    const float* W0      = (const float*)d_in[4];
    const float* W1      = (const float*)d_in[5];
    const float* centers = (const float*)d_in[6];
    const float* widths  = (const float*)d_in[7];
    const float* proj_w  = (const float*)d_in[8];
    const float* proj_b  = (const float*)d_in[9];
    const float* gamma   = (const float*)d_in[10];
    const float* beta    = (const float*)d_in[11];

    float* out  = (float*)d_out;
    int*   wsi  = (int*)d_ws;
    float* ew   = (float*)d_ws;
    int*   deg  = wsi + WS_DEG;
    int*   offs = wsi + WS_OFFS;
    int*   curs = wsi + WS_CURSOR;
    int*   esrc = wsi + WS_ESRC;

    hipMemsetAsync(d_ws, 0, (size_t)(WS_DEG + N_NODES) * sizeof(int), stream);

    const int eb = (N_EDGES + 255) / 256;
    hist_ew <<<eb, 256, 0, stream>>>(ei, pos, centers, widths, proj_w, proj_b, deg, ew);
    scan_deg<<<1, 1024, 0, stream>>>(deg, offs, curs);
    fill_csr<<<eb, 256, 0, stream>>>(ei, curs, esrc);

    const int nb = (N_NODES * 64 + 255) / 256;
    gather_pass<<<nb, 256, 0, stream>>>(x, offs, esrc, out);

    const int tb = (N_NODES + 255) / 256;   // lane-owns-node
    scalar_pass<<<tb, 256, 0, stream>>>(out, W0, gamma, beta, ew);
    vector_pass<<<tb, 256, 0, stream>>>(out, W1, ew);
}